// Round 1
// baseline (542.046 us; speedup 1.0000x reference)
//
#include <hip/hip_runtime.h>

#define Hh 160
#define Ww 160
#define HW 25600
#define Bb 8
#define Cc 64
#define Oo 64
#define NPIX (Bb * HW)   // 204800

// ---------------- prep: transpose w_dcn (O,C,9) -> wt (C*9, O); BN inv/shift ----
__global__ __launch_bounds__(256) void prep_kernel(
    const float* __restrict__ w_dcn, const float* __restrict__ gamma,
    const float* __restrict__ beta, const float* __restrict__ run_mean,
    const float* __restrict__ run_var,
    float* __restrict__ wt, float* __restrict__ invshift)
{
    int i = blockIdx.x * 256 + threadIdx.x;
    if (i < Oo * Cc * 9) {
        int o   = i / (Cc * 9);
        int rem = i % (Cc * 9);          // rem = c*9 + k
        wt[rem * Oo + o] = w_dcn[i];
    }
    if (i < Oo) {
        float inv = gamma[i] / sqrtf(run_var[i] + 1e-5f);
        invshift[i]      = inv;
        invshift[Oo + i] = beta[i] - run_mean[i] * inv;
    }
}

// ---------------- offset conv: (B,64,H,W) -> (B,18,H,W), 3x3 pad 1 -------------
__global__ __launch_bounds__(256) void offconv_kernel(
    const float* __restrict__ x, const float* __restrict__ w_off,
    const float* __restrict__ b_off, float* __restrict__ offs)
{
    int pix = blockIdx.x * 256 + threadIdx.x;   // exactly NPIX threads
    int b  = pix / HW;
    int hw = pix % HW;
    int h  = hw / Ww;
    int w  = hw % Ww;

    float acc[18];
#pragma unroll
    for (int oc = 0; oc < 18; ++oc) acc[oc] = b_off[oc];

    const float* xb = x + (size_t)b * Cc * HW;
    for (int ic = 0; ic < Cc; ++ic) {
        const float* xc = xb + ic * HW;
        float xv[9];
#pragma unroll
        for (int dy = 0; dy < 3; ++dy) {
#pragma unroll
            for (int dx = 0; dx < 3; ++dx) {
                int hh = h + dy - 1;
                int ww = w + dx - 1;
                bool ok = (hh >= 0) & (hh < Hh) & (ww >= 0) & (ww < Ww);
                xv[dy * 3 + dx] = ok ? xc[hh * Ww + ww] : 0.0f;
            }
        }
        const float* wr = w_off + ic * 9;   // w_off[(oc*64+ic)*9 + k], uniform
#pragma unroll
        for (int oc = 0; oc < 18; ++oc) {
#pragma unroll
            for (int k = 0; k < 9; ++k)
                acc[oc] += xv[k] * wr[oc * Cc * 9 + k];
        }
    }

    float* op = offs + (size_t)b * 18 * HW + hw;
#pragma unroll
    for (int oc = 0; oc < 18; ++oc) op[oc * HW] = acc[oc];
}

// ---------------- fused: deform sample + (C*9 x O) projection + BN + ReLU ------
__global__ __launch_bounds__(256) void dcn_kernel(
    const float* __restrict__ x, const float* __restrict__ offs,
    const float* __restrict__ wt, const float* __restrict__ b_dcn,
    const float* __restrict__ invshift, float* __restrict__ out)
{
    int pix = blockIdx.x * 256 + threadIdx.x;
    int b  = pix / HW;
    int hw = pix % HW;
    int h  = hw / Ww;
    int w  = hw % Ww;

    float acc[Oo];
#pragma unroll
    for (int o = 0; o < Oo; ++o) acc[o] = 0.0f;

    const float* xb = x + (size_t)b * Cc * HW;
    const float* ob = offs + (size_t)b * 18 * HW + hw;

    for (int k = 0; k < 9; ++k) {
        float offy = ob[(2 * k) * HW];
        float offx = ob[(2 * k + 1) * HW];
        float py = (float)h + (float)(k / 3 - 1) + offy;
        float px = (float)w + (float)(k % 3 - 1) + offx;
        float y0f = floorf(py), x0f = floorf(px);
        float fy = py - y0f, fx = px - x0f;
        int y0 = (int)y0f, x0 = (int)x0f;
        int y1 = y0 + 1,  x1 = x0 + 1;

        bool vy0 = (y0 >= 0) & (y0 <= Hh - 1);
        bool vy1 = (y1 >= 0) & (y1 <= Hh - 1);
        bool vx0 = (x0 >= 0) & (x0 <= Ww - 1);
        bool vx1 = (x1 >= 0) & (x1 <= Ww - 1);

        float wy0 = 1.0f - fy, wy1 = fy;
        float wx0 = 1.0f - fx, wx1 = fx;
        float w00 = (vy0 & vx0) ? wy0 * wx0 : 0.0f;
        float w01 = (vy0 & vx1) ? wy0 * wx1 : 0.0f;
        float w10 = (vy1 & vx0) ? wy1 * wx0 : 0.0f;
        float w11 = (vy1 & vx1) ? wy1 * wx1 : 0.0f;

        int cy0 = min(max(y0, 0), Hh - 1), cy1 = min(max(y1, 0), Hh - 1);
        int cx0 = min(max(x0, 0), Ww - 1), cx1 = min(max(x1, 0), Ww - 1);
        int i00 = cy0 * Ww + cx0, i01 = cy0 * Ww + cx1;
        int i10 = cy1 * Ww + cx0, i11 = cy1 * Ww + cx1;

        const float* wk = wt + k * Oo;      // wt[(c*9+k)*64 + o], uniform index
        for (int c = 0; c < Cc; ++c) {
            const float* xc = xb + c * HW;
            float col = w00 * xc[i00] + w01 * xc[i01]
                      + w10 * xc[i10] + w11 * xc[i11];
            const float* wck = wk + c * 9 * Oo;
#pragma unroll
            for (int o = 0; o < Oo; ++o) acc[o] += col * wck[o];
        }
    }

    float* outp = out + (size_t)b * Oo * HW + hw;
#pragma unroll
    for (int o = 0; o < Oo; ++o) {
        float z = (acc[o] + b_dcn[o]) * invshift[o] + invshift[Oo + o];
        outp[o * HW] = fmaxf(z, 0.0f);
    }
}

extern "C" void kernel_launch(void* const* d_in, const int* in_sizes, int n_in,
                              void* d_out, int out_size, void* d_ws, size_t ws_size,
                              hipStream_t stream) {
    const float* x        = (const float*)d_in[0];
    const float* w_off    = (const float*)d_in[1];
    const float* b_off    = (const float*)d_in[2];
    const float* w_dcn    = (const float*)d_in[3];
    const float* b_dcn    = (const float*)d_in[4];
    const float* gamma    = (const float*)d_in[5];
    const float* beta     = (const float*)d_in[6];
    const float* run_mean = (const float*)d_in[7];
    const float* run_var  = (const float*)d_in[8];
    float* out = (float*)d_out;

    // workspace layout
    float* offs     = (float*)d_ws;                                // B*18*HW floats
    float* wt       = offs + (size_t)Bb * 18 * HW;                 // 64*9*64 floats
    float* invshift = wt + (size_t)Cc * 9 * Oo;                    // 128 floats

    prep_kernel<<<(Oo * Cc * 9 + 255) / 256, 256, 0, stream>>>(
        w_dcn, gamma, beta, run_mean, run_var, wt, invshift);

    offconv_kernel<<<NPIX / 256, 256, 0, stream>>>(x, w_off, b_off, offs);

    dcn_kernel<<<NPIX / 256, 256, 0, stream>>>(x, offs, wt, b_dcn, invshift, out);
}

// Round 2
// 506.950 us; speedup vs baseline: 1.0692x; 1.0692x over previous
//
#include <hip/hip_runtime.h>

#define Hh 160
#define Ww 160
#define HW 25600
#define Bb 8
#define Cc 64
#define Oo 64
#define NPIX (Bb * HW)   // 204800
#define PADC 72          // LDS row stride in bf16 elems (64 + 8 pad, keeps 16B align)

typedef __bf16 bf16x8 __attribute__((ext_vector_type(8)));
typedef float  f32x4  __attribute__((ext_vector_type(4)));

__device__ inline unsigned pack_bf2(float a, float b) {
    unsigned ua = __float_as_uint(a);
    unsigned ub = __float_as_uint(b);
    ua = (ua + 0x7FFFu + ((ua >> 16) & 1u)) >> 16;   // RNE f32->bf16
    ub = (ub + 0x7FFFu + ((ub >> 16) & 1u)) >> 16;
    return ua | (ub << 16);
}

// ---- prep: w_dcn (O,C,9) fp32 -> wtb[k][o][c] bf16 ; fold BN+bias -> scaleb ----
__global__ __launch_bounds__(256) void prep_kernel(
    const float* __restrict__ w_dcn, const float* __restrict__ b_dcn,
    const float* __restrict__ gamma, const float* __restrict__ beta,
    const float* __restrict__ run_mean, const float* __restrict__ run_var,
    unsigned short* __restrict__ wtb, float* __restrict__ scaleb)
{
    int i = blockIdx.x * 256 + threadIdx.x;
    if (i < 9 * Cc * Oo) {
        int k = i >> 12;          // 4096 = Cc*Oo per tap
        int rem = i & 4095;
        int o = rem >> 6, c = rem & 63;
        float v = w_dcn[(o * Cc + c) * 9 + k];
        unsigned u = __float_as_uint(v);
        wtb[i] = (unsigned short)((u + 0x7FFFu + ((u >> 16) & 1u)) >> 16);
    }
    if (i < Oo) {
        float inv = gamma[i] * rsqrtf(run_var[i] + 1e-5f);
        scaleb[i]      = inv;
        scaleb[Oo + i] = b_dcn[i] * inv + (beta[i] - run_mean[i] * inv);
    }
}

// ---- offset conv: (B,64,H,W) -> (B,18,H,W), 3x3 pad 1 (fp32, unchanged) -------
__global__ __launch_bounds__(256) void offconv_kernel(
    const float* __restrict__ x, const float* __restrict__ w_off,
    const float* __restrict__ b_off, float* __restrict__ offs)
{
    int pix = blockIdx.x * 256 + threadIdx.x;
    int b  = pix / HW;
    int hw = pix % HW;
    int h  = hw / Ww;
    int w  = hw % Ww;

    float acc[18];
#pragma unroll
    for (int oc = 0; oc < 18; ++oc) acc[oc] = b_off[oc];

    const float* xb = x + (size_t)b * Cc * HW;
    for (int ic = 0; ic < Cc; ++ic) {
        const float* xc = xb + ic * HW;
        float xv[9];
#pragma unroll
        for (int dy = 0; dy < 3; ++dy) {
#pragma unroll
            for (int dx = 0; dx < 3; ++dx) {
                int hh = h + dy - 1;
                int ww = w + dx - 1;
                bool ok = (hh >= 0) & (hh < Hh) & (ww >= 0) & (ww < Ww);
                xv[dy * 3 + dx] = ok ? xc[hh * Ww + ww] : 0.0f;
            }
        }
        const float* wr = w_off + ic * 9;
#pragma unroll
        for (int oc = 0; oc < 18; ++oc) {
#pragma unroll
            for (int k = 0; k < 9; ++k)
                acc[oc] += xv[k] * wr[oc * Cc * 9 + k];
        }
    }

    float* op = offs + (size_t)b * 18 * HW + hw;
#pragma unroll
    for (int oc = 0; oc < 18; ++oc) op[oc * HW] = acc[oc];
}

// ---- fused deform-sample + MFMA projection + BN + ReLU ------------------------
// Block: 256 thr = 4 waves, 64 consecutive pixels, all 64 outputs, K per-tap.
__global__ __launch_bounds__(256) void dcn_kernel(
    const float* __restrict__ x, const float* __restrict__ offs,
    const unsigned short* __restrict__ wtb, const float* __restrict__ scaleb,
    float* __restrict__ out)
{
    __shared__ __align__(16) char smem[18432];
    short* cols = (short*)smem;              // [64 px][PADC] bf16
    short* wlds = (short*)(smem + 9216);     // [64 o ][PADC] bf16
    float* obuf = (float*)smem;              // epilogue: [64 o][66] fp32 (union)

    int t  = threadIdx.x;
    int p  = t & 63;            // pixel within block (producer role)
    int cg = t >> 6;            // channel group 0..3 (16 c each)
    int lane = t & 63, wv = t >> 6;          // consumer role
    int m = lane & 15, quad = lane >> 4;

    int blk = blockIdx.x;
    int b   = blk / 400;                     // 400 blocks per image (HW/64)
    int hw0 = (blk % 400) * 64;
    int hw  = hw0 + p;
    int h   = hw / Ww, w = hw % Ww;

    f32x4 acc0 = {0,0,0,0}, acc1 = {0,0,0,0}, acc2 = {0,0,0,0}, acc3 = {0,0,0,0};

    const float* xb = x + (size_t)b * Cc * HW;
    const float* obp = offs + (size_t)b * 18 * HW + hw;
    const uint4* wtb4 = (const uint4*)wtb;   // 8 bf16 per uint4

    for (int k = 0; k < 9; ++k) {
        // ---- stage tap-k weights [64 o][64 c] -> wlds (padded rows) ----
#pragma unroll
        for (int q = t; q < 512; q += 256) {
            uint4 v = wtb4[k * 512 + q];
            int o = q >> 3, seg = q & 7;
            *(uint4*)((char*)wlds + o * (PADC * 2) + seg * 16) = v;
        }

        // ---- bilinear sample 16 channels for pixel p -> cols ----
        float offy = obp[(2 * k) * HW];
        float offx = obp[(2 * k + 1) * HW];
        float py = (float)(h + k / 3 - 1) + offy;
        float px = (float)(w + k % 3 - 1) + offx;
        float y0f = floorf(py), x0f = floorf(px);
        float fy = py - y0f, fx = px - x0f;
        int y0 = (int)y0f, x0i = (int)x0f;
        int y1 = y0 + 1, x1 = x0i + 1;
        bool vy0 = (y0 >= 0) & (y0 < Hh), vy1 = (y1 >= 0) & (y1 < Hh);
        bool vx0 = (x0i >= 0) & (x0i < Ww), vx1 = (x1 >= 0) & (x1 < Ww);
        float w00 = (vy0 & vx0) ? (1.0f - fy) * (1.0f - fx) : 0.0f;
        float w01 = (vy0 & vx1) ? (1.0f - fy) * fx : 0.0f;
        float w10 = (vy1 & vx0) ? fy * (1.0f - fx) : 0.0f;
        float w11 = (vy1 & vx1) ? fy * fx : 0.0f;
        int cy0 = min(max(y0, 0), Hh - 1), cy1 = min(max(y1, 0), Hh - 1);
        int cx0 = min(max(x0i, 0), Ww - 1), cx1 = min(max(x1, 0), Ww - 1);
        int i00 = cy0 * Ww + cx0, i01 = cy0 * Ww + cx1;
        int i10 = cy1 * Ww + cx0, i11 = cy1 * Ww + cx1;

        unsigned* cdst = (unsigned*)cols + p * (PADC / 2) + cg * 8;
        const float* xc = xb + (cg * 16) * HW;
#pragma unroll
        for (int cc = 0; cc < 16; cc += 2) {
            float v0 = w00 * xc[i00] + w01 * xc[i01] + w10 * xc[i10] + w11 * xc[i11];
            xc += HW;
            float v1 = w00 * xc[i00] + w01 * xc[i01] + w10 * xc[i10] + w11 * xc[i11];
            xc += HW;
            cdst[cc >> 1] = pack_bf2(v0, v1);
        }
        __syncthreads();

        // ---- MFMA: wave wv handles pixels [wv*16, wv*16+16), all 64 o ----
        const short* arow = cols + (wv * 16 + m) * PADC + quad * 8;
        bf16x8 a0 = *(const bf16x8*)(arow);
        bf16x8 a1 = *(const bf16x8*)(arow + 32);
        {
            const short* brow = wlds + m * PADC + quad * 8;
            bf16x8 b0 = *(const bf16x8*)(brow);
            bf16x8 b1 = *(const bf16x8*)(brow + 32);
            acc0 = __builtin_amdgcn_mfma_f32_16x16x32_bf16(a0, b0, acc0, 0, 0, 0);
            acc0 = __builtin_amdgcn_mfma_f32_16x16x32_bf16(a1, b1, acc0, 0, 0, 0);
            brow += 16 * PADC;
            b0 = *(const bf16x8*)(brow);
            b1 = *(const bf16x8*)(brow + 32);
            acc1 = __builtin_amdgcn_mfma_f32_16x16x32_bf16(a0, b0, acc1, 0, 0, 0);
            acc1 = __builtin_amdgcn_mfma_f32_16x16x32_bf16(a1, b1, acc1, 0, 0, 0);
            brow += 16 * PADC;
            b0 = *(const bf16x8*)(brow);
            b1 = *(const bf16x8*)(brow + 32);
            acc2 = __builtin_amdgcn_mfma_f32_16x16x32_bf16(a0, b0, acc2, 0, 0, 0);
            acc2 = __builtin_amdgcn_mfma_f32_16x16x32_bf16(a1, b1, acc2, 0, 0, 0);
            brow += 16 * PADC;
            b0 = *(const bf16x8*)(brow);
            b1 = *(const bf16x8*)(brow + 32);
            acc3 = __builtin_amdgcn_mfma_f32_16x16x32_bf16(a0, b0, acc3, 0, 0, 0);
            acc3 = __builtin_amdgcn_mfma_f32_16x16x32_bf16(a1, b1, acc3, 0, 0, 0);
        }
        __syncthreads();   // protect cols/wlds before next tap's producer writes
    }

    // ---- epilogue: transpose via LDS, fused BN+ReLU, coalesced stores ----
    // C/D layout: n(col)=lane&15 -> o = nt*16+m ; m(row)=quad*4+reg -> pixel.
#pragma unroll
    for (int nt = 0; nt < 4; ++nt) {
        f32x4 a = (nt == 0) ? acc0 : (nt == 1) ? acc1 : (nt == 2) ? acc2 : acc3;
        int o = nt * 16 + m;
#pragma unroll
        for (int r = 0; r < 4; ++r) {
            int pp = wv * 16 + quad * 4 + r;
            obuf[o * 66 + pp] = a[r];
        }
    }
    __syncthreads();
#pragma unroll
    for (int it = 0; it < 16; ++it) {
        int o = wv * 16 + it;
        float sc = scaleb[o];
        float bs = scaleb[Oo + o];
        float v = obuf[o * 66 + lane];
        out[((size_t)b * Oo + o) * HW + hw0 + lane] = fmaxf(v * sc + bs, 0.0f);
    }
}

extern "C" void kernel_launch(void* const* d_in, const int* in_sizes, int n_in,
                              void* d_out, int out_size, void* d_ws, size_t ws_size,
                              hipStream_t stream) {
    const float* x        = (const float*)d_in[0];
    const float* w_off    = (const float*)d_in[1];
    const float* b_off    = (const float*)d_in[2];
    const float* w_dcn    = (const float*)d_in[3];
    const float* b_dcn    = (const float*)d_in[4];
    const float* gamma    = (const float*)d_in[5];
    const float* beta     = (const float*)d_in[6];
    const float* run_mean = (const float*)d_in[7];
    const float* run_var  = (const float*)d_in[8];
    float* out = (float*)d_out;

    // workspace layout
    float* offs            = (float*)d_ws;                       // B*18*HW floats
    unsigned short* wtb    = (unsigned short*)(offs + (size_t)Bb * 18 * HW); // 9*64*64 bf16
    float* scaleb          = (float*)(wtb + 9 * Cc * Oo);        // 128 floats

    prep_kernel<<<(9 * Cc * Oo + 255) / 256, 256, 0, stream>>>(
        w_dcn, b_dcn, gamma, beta, run_mean, run_var, wtb, scaleb);

    offconv_kernel<<<NPIX / 256, 256, 0, stream>>>(x, w_off, b_off, offs);

    dcn_kernel<<<NPIX / 64, 256, 0, stream>>>(x, offs, wtb, scaleb, out);
}

// Round 3
// 274.167 us; speedup vs baseline: 1.9771x; 1.8491x over previous
//
#include <hip/hip_runtime.h>

#define Hh 160
#define Ww 160
#define HW 25600
#define Bb 8
#define Cc 64
#define Oo 64
#define NPIX (Bb * HW)   // 204800
#define PADC 72          // LDS row stride in bf16 elems

typedef __bf16 bf16x8 __attribute__((ext_vector_type(8)));
typedef float  f32x4  __attribute__((ext_vector_type(4)));
typedef float  f32x2  __attribute__((ext_vector_type(2)));

__device__ inline unsigned rnd_bf(float a) {
    unsigned u = __float_as_uint(a);
    return (u + 0x7FFFu + ((u >> 16) & 1u)) >> 16;   // RNE f32->bf16
}
__device__ inline unsigned pack_bf2(float a, float b) {
    return rnd_bf(a) | (rnd_bf(b) << 16);
}
__device__ inline f32x2 up2(unsigned u) {
    f32x2 r;
    r.x = __uint_as_float(u << 16);
    r.y = __uint_as_float(u & 0xffff0000u);
    return r;
}
__device__ inline unsigned blend4(unsigned u00, unsigned u01, unsigned u10, unsigned u11,
                                  float w00, float w01, float w10, float w11) {
    f32x2 r = up2(u00) * w00 + up2(u01) * w01 + up2(u10) * w10 + up2(u11) * w11;
    return pack_bf2(r.x, r.y);
}

// ---- prep: wtb[k][o 64][c] bf16 ; woffb[k][o 32 pad][c] bf16 ; BN fold --------
__global__ __launch_bounds__(256) void prep_kernel(
    const float* __restrict__ w_dcn, const float* __restrict__ b_dcn,
    const float* __restrict__ w_off,
    const float* __restrict__ gamma, const float* __restrict__ beta,
    const float* __restrict__ run_mean, const float* __restrict__ run_var,
    unsigned short* __restrict__ wtb, unsigned short* __restrict__ woffb,
    float* __restrict__ scaleb)
{
    int i = blockIdx.x * 256 + threadIdx.x;
    if (i < 9 * Oo * Cc) {                 // wtb: [k][o][c]
        int k = i >> 12, rem = i & 4095;
        int o = rem >> 6, c = rem & 63;
        wtb[i] = (unsigned short)rnd_bf(w_dcn[(o * Cc + c) * 9 + k]);
    }
    if (i < 9 * 32 * Cc) {                 // woffb: [k][o pad32][c]
        int k = i >> 11, rem = i & 2047;
        int o = rem >> 6, c = rem & 63;
        float v = (o < 18) ? w_off[(o * Cc + c) * 9 + k] : 0.0f;
        woffb[i] = (unsigned short)rnd_bf(v);
    }
    if (i < Oo) {
        float inv = gamma[i] * rsqrtf(run_var[i] + 1e-5f);
        scaleb[i]      = inv;
        scaleb[Oo + i] = b_dcn[i] * inv + (beta[i] - run_mean[i] * inv);
    }
}

// ---- transpose x: NCHW fp32 -> NHWC bf16 --------------------------------------
__global__ __launch_bounds__(256) void xpose_kernel(
    const float* __restrict__ x, unsigned short* __restrict__ xhwc)
{
    int pix = blockIdx.x * 256 + threadIdx.x;
    int b = pix / HW, hw = pix % HW;
    const float* xp = x + (size_t)b * Cc * HW + hw;
    uint4* dst = (uint4*)(xhwc + (size_t)pix * 64);
#pragma unroll
    for (int g = 0; g < 8; ++g) {
        unsigned u0 = pack_bf2(xp[(g * 8 + 0) * HW], xp[(g * 8 + 1) * HW]);
        unsigned u1 = pack_bf2(xp[(g * 8 + 2) * HW], xp[(g * 8 + 3) * HW]);
        unsigned u2 = pack_bf2(xp[(g * 8 + 4) * HW], xp[(g * 8 + 5) * HW]);
        unsigned u3 = pack_bf2(xp[(g * 8 + 6) * HW], xp[(g * 8 + 7) * HW]);
        dst[g] = make_uint4(u0, u1, u2, u3);
    }
}

// ---- fused: offset-conv(MFMA) + deform-sample + projection(MFMA) + BN + ReLU --
// Block: 256 thr = 4 waves, 64 px; XCD slab swizzle -> 1 image per XCD.
__global__ __launch_bounds__(256) void dcn_kernel(
    const unsigned short* __restrict__ xhwc,
    const unsigned short* __restrict__ wtb,
    const unsigned short* __restrict__ woffb,
    const float* __restrict__ b_off,
    const float* __restrict__ scaleb,
    float* __restrict__ out)
{
    __shared__ __align__(16) char smem[23808];
    short* cols = (short*)smem;              // [64 px][PADC] bf16
    short* wlds = (short*)(smem + 9216);     // [64 rows][PADC] bf16
    float* offb = (float*)(smem + 18432);    // [64 px][21] fp32
    float* obuf = (float*)smem;              // epilogue [64 o][66] fp32 (union)

    const int t = threadIdx.x;
    const int p = t & 63, cg = t >> 6;
    const int lane = t & 63, wv = t >> 6;
    const int m = lane & 15, quad = lane >> 4;

    int blk = blockIdx.x;
    int nb  = (blk & 7) * 400 + (blk >> 3);  // XCD slab swizzle
    int b   = nb / 400;
    int hw0 = (nb % 400) * 64;
    int hw  = hw0 + p;
    int h   = hw / Ww, w = hw % Ww;

    const size_t bbase = (size_t)b * HW;
    const uint4* wtb4   = (const uint4*)wtb;
    const uint4* woffb4 = (const uint4*)woffb;

    // ================= phase 1: offset conv via MFMA =================
    f32x4 oa0 = {0, 0, 0, 0}, oa1 = {0, 0, 0, 0};
    for (int k = 0; k < 9; ++k) {
        {   // stage w_off tap k: 32 rows x 64c (256 chunks, 1/thread)
            uint4 v = woffb4[k * 256 + t];
            *(uint4*)((char*)wlds + (t >> 3) * 144 + (t & 7) * 16) = v;
        }
        int hp = h + (k / 3) - 1, wp = w + (k % 3) - 1;
        bool ok = (hp >= 0) & (hp < Hh) & (wp >= 0) & (wp < Ww);
        int hps = min(max(hp, 0), Hh - 1), wps = min(max(wp, 0), Ww - 1);
        const uint4* src = (const uint4*)(xhwc + (bbase + hps * Ww + wps) * 64);
        uint4 v0 = src[cg * 2];
        uint4 v1 = src[cg * 2 + 1];
        if (!ok) { v0 = make_uint4(0,0,0,0); v1 = make_uint4(0,0,0,0); }
        *(uint4*)((char*)cols + p * 144 + cg * 32)      = v0;
        *(uint4*)((char*)cols + p * 144 + cg * 32 + 16) = v1;
        __syncthreads();

        const short* arow = cols + (wv * 16 + m) * PADC + quad * 8;
        bf16x8 a0 = *(const bf16x8*)arow;
        bf16x8 a1 = *(const bf16x8*)(arow + 32);
        const short* brow = wlds + m * PADC + quad * 8;
        bf16x8 b0 = *(const bf16x8*)brow;
        bf16x8 b1 = *(const bf16x8*)(brow + 32);
        oa0 = __builtin_amdgcn_mfma_f32_16x16x32_bf16(a0, b0, oa0, 0, 0, 0);
        oa0 = __builtin_amdgcn_mfma_f32_16x16x32_bf16(a1, b1, oa0, 0, 0, 0);
        brow += 16 * PADC;
        b0 = *(const bf16x8*)brow;
        b1 = *(const bf16x8*)(brow + 32);
        oa1 = __builtin_amdgcn_mfma_f32_16x16x32_bf16(a0, b0, oa1, 0, 0, 0);
        oa1 = __builtin_amdgcn_mfma_f32_16x16x32_bf16(a1, b1, oa1, 0, 0, 0);
        __syncthreads();
    }
    // offsets -> LDS (stride 21 -> conflict-free reads)
#pragma unroll
    for (int nt = 0; nt < 2; ++nt) {
        f32x4 a = nt ? oa1 : oa0;
        int o = nt * 16 + m;
        if (o < 18) {
            float bo = b_off[o];
#pragma unroll
            for (int r = 0; r < 4; ++r) {
                int pp = wv * 16 + quad * 4 + r;
                offb[pp * 21 + o] = a[r] + bo;
            }
        }
    }
    __syncthreads();

    // ================= phase 2: deform sample + projection =================
    f32x4 c0 = {0,0,0,0}, c1 = {0,0,0,0}, c2 = {0,0,0,0}, c3 = {0,0,0,0};
    const unsigned short* xb = xhwc + bbase * 64 + cg * 16;

    for (int k = 0; k < 9; ++k) {
#pragma unroll
        for (int q = t; q < 512; q += 256) {   // stage w_dcn tap k: 64 rows
            uint4 v = wtb4[k * 512 + q];
            *(uint4*)((char*)wlds + (q >> 3) * 144 + (q & 7) * 16) = v;
        }
        float offy = offb[p * 21 + 2 * k];
        float offx = offb[p * 21 + 2 * k + 1];
        float py = (float)(h + k / 3 - 1) + offy;
        float px = (float)(w + k % 3 - 1) + offx;
        float y0f = floorf(py), x0f = floorf(px);
        float fy = py - y0f, fx = px - x0f;
        int y0 = (int)y0f, x0i = (int)x0f;
        int y1 = y0 + 1, x1 = x0i + 1;
        bool vy0 = (y0 >= 0) & (y0 < Hh), vy1 = (y1 >= 0) & (y1 < Hh);
        bool vx0 = (x0i >= 0) & (x0i < Ww), vx1 = (x1 >= 0) & (x1 < Ww);
        float w00 = (vy0 & vx0) ? (1.0f - fy) * (1.0f - fx) : 0.0f;
        float w01 = (vy0 & vx1) ? (1.0f - fy) * fx : 0.0f;
        float w10 = (vy1 & vx0) ? fy * (1.0f - fx) : 0.0f;
        float w11 = (vy1 & vx1) ? fy * fx : 0.0f;
        int cy0 = min(max(y0, 0), Hh - 1), cy1 = min(max(y1, 0), Hh - 1);
        int cx0 = min(max(x0i, 0), Ww - 1), cx1 = min(max(x1, 0), Ww - 1);

        const uint4* p00 = (const uint4*)(xb + (size_t)(cy0 * Ww + cx0) * 64);
        const uint4* p01 = (const uint4*)(xb + (size_t)(cy0 * Ww + cx1) * 64);
        const uint4* p10 = (const uint4*)(xb + (size_t)(cy1 * Ww + cx0) * 64);
        const uint4* p11 = (const uint4*)(xb + (size_t)(cy1 * Ww + cx1) * 64);
        uint4 a00 = p00[0], b00 = p00[1];
        uint4 a01 = p01[0], b01 = p01[1];
        uint4 a10 = p10[0], b10 = p10[1];
        uint4 a11 = p11[0], b11 = p11[1];

        uint4 o0, o1;
        o0.x = blend4(a00.x, a01.x, a10.x, a11.x, w00, w01, w10, w11);
        o0.y = blend4(a00.y, a01.y, a10.y, a11.y, w00, w01, w10, w11);
        o0.z = blend4(a00.z, a01.z, a10.z, a11.z, w00, w01, w10, w11);
        o0.w = blend4(a00.w, a01.w, a10.w, a11.w, w00, w01, w10, w11);
        o1.x = blend4(b00.x, b01.x, b10.x, b11.x, w00, w01, w10, w11);
        o1.y = blend4(b00.y, b01.y, b10.y, b11.y, w00, w01, w10, w11);
        o1.z = blend4(b00.z, b01.z, b10.z, b11.z, w00, w01, w10, w11);
        o1.w = blend4(b00.w, b01.w, b10.w, b11.w, w00, w01, w10, w11);
        *(uint4*)((char*)cols + p * 144 + cg * 32)      = o0;
        *(uint4*)((char*)cols + p * 144 + cg * 32 + 16) = o1;
        __syncthreads();

        const short* arow = cols + (wv * 16 + m) * PADC + quad * 8;
        bf16x8 a0 = *(const bf16x8*)arow;
        bf16x8 a1 = *(const bf16x8*)(arow + 32);
        const short* brow = wlds + m * PADC + quad * 8;
        bf16x8 bb0 = *(const bf16x8*)brow;
        bf16x8 bb1 = *(const bf16x8*)(brow + 32);
        c0 = __builtin_amdgcn_mfma_f32_16x16x32_bf16(a0, bb0, c0, 0, 0, 0);
        c0 = __builtin_amdgcn_mfma_f32_16x16x32_bf16(a1, bb1, c0, 0, 0, 0);
        brow += 16 * PADC;
        bb0 = *(const bf16x8*)brow; bb1 = *(const bf16x8*)(brow + 32);
        c1 = __builtin_amdgcn_mfma_f32_16x16x32_bf16(a0, bb0, c1, 0, 0, 0);
        c1 = __builtin_amdgcn_mfma_f32_16x16x32_bf16(a1, bb1, c1, 0, 0, 0);
        brow += 16 * PADC;
        bb0 = *(const bf16x8*)brow; bb1 = *(const bf16x8*)(brow + 32);
        c2 = __builtin_amdgcn_mfma_f32_16x16x32_bf16(a0, bb0, c2, 0, 0, 0);
        c2 = __builtin_amdgcn_mfma_f32_16x16x32_bf16(a1, bb1, c2, 0, 0, 0);
        brow += 16 * PADC;
        bb0 = *(const bf16x8*)brow; bb1 = *(const bf16x8*)(brow + 32);
        c3 = __builtin_amdgcn_mfma_f32_16x16x32_bf16(a0, bb0, c3, 0, 0, 0);
        c3 = __builtin_amdgcn_mfma_f32_16x16x32_bf16(a1, bb1, c3, 0, 0, 0);
        __syncthreads();
    }

    // ---- epilogue: LDS transpose + BN + ReLU, coalesced stores ----
#pragma unroll
    for (int nt = 0; nt < 4; ++nt) {
        f32x4 a = (nt == 0) ? c0 : (nt == 1) ? c1 : (nt == 2) ? c2 : c3;
        int o = nt * 16 + m;
#pragma unroll
        for (int r = 0; r < 4; ++r)
            obuf[o * 66 + wv * 16 + quad * 4 + r] = a[r];
    }
    __syncthreads();
#pragma unroll
    for (int it = 0; it < 16; ++it) {
        int o = wv * 16 + it;
        float sc = scaleb[o];
        float bs = scaleb[Oo + o];
        float v = obuf[o * 66 + lane];
        out[((size_t)b * Oo + o) * HW + hw0 + lane] = fmaxf(v * sc + bs, 0.0f);
    }
}

extern "C" void kernel_launch(void* const* d_in, const int* in_sizes, int n_in,
                              void* d_out, int out_size, void* d_ws, size_t ws_size,
                              hipStream_t stream) {
    const float* x        = (const float*)d_in[0];
    const float* w_off    = (const float*)d_in[1];
    const float* b_off    = (const float*)d_in[2];
    const float* w_dcn    = (const float*)d_in[3];
    const float* b_dcn    = (const float*)d_in[4];
    const float* gamma    = (const float*)d_in[5];
    const float* beta     = (const float*)d_in[6];
    const float* run_mean = (const float*)d_in[7];
    const float* run_var  = (const float*)d_in[8];
    float* out = (float*)d_out;

    // workspace: xhwc (26.2 MB) | wtb | woffb | scaleb
    unsigned short* xhwc  = (unsigned short*)d_ws;
    unsigned short* wtb   = xhwc + (size_t)NPIX * 64;          // 9*64*64 bf16
    unsigned short* woffb = wtb + 9 * Oo * Cc;                 // 9*32*64 bf16
    float* scaleb         = (float*)(woffb + 9 * 32 * Cc);     // 128 floats

    prep_kernel<<<(9 * Oo * Cc + 255) / 256, 256, 0, stream>>>(
        w_dcn, b_dcn, w_off, gamma, beta, run_mean, run_var, wtb, woffb, scaleb);

    xpose_kernel<<<NPIX / 256, 256, 0, stream>>>(x, xhwc);

    dcn_kernel<<<NPIX / 64, 256, 0, stream>>>(xhwc, wtb, woffb, b_off, scaleb, out);
}